// Round 15
// baseline (21829.082 us; speedup 1.0000x reference)
//
#include <hip/hip_runtime.h>
#include <stdint.h>

// LSTM (linear cell/output act) h_last. S=8192, D_IN=1024, H=2048.
// Persistent: 256 WGs x 256 thr, 1 WG/CU. WG owns 8 h-indices (32 cols).
// Thread (kc=tid>>3, cg=tid&7): 4 gate-cols of h-index cg, k-chunk kc.
//   U slice in regs ureg[4][32], W slice in regs wreg[4][16] (f16x2).
// Exchange: producer WG publishes 8 h as FOUR u64 {tag32|f16x2} (32 B).
// GATHER (r15): DUAL-BATCH adaptive pace. sleep(pace-4) -> issue PROBE ->
// sleep(4) -> issue SAFE -> x-dot -> check probe (hit: use it, pace-1/step)
// else check safe (hit: use it, hold pace — NO fallback, NO late publish)
// else true straggler: pace+8 + paced fallback poll. Deliberate boundary
// probing becomes FREE, deleting the ~28-WGs-miss-late-per-step dynamics
// that inflated r11's equilibrium (all-to-all turns any straggler into
// everyone's next-step floor).
// POST-MORTEM LEDGER:
//  - r2: partial unroll -> ureg/wreg in scratch (VGPR=80, 207GB, 2.7x).
//  - r3: guarded per-slot polls serialize (8 x LLC RT/round).
//  - r4: 64B tight polls -> contention collapse (38ms).
//  - r5: 32B + sleep(2) = 26.2ms best blind-poll design.
//  - r6: depth-2 no-sleep -> 32.3ms (traffic storm).
//  - r7: 8B tag + 32B confirm = 27.7ms (extra serial RT).
//  - r8/r9: sc0 XCD-L2 mirror never engaged; abandoned.
//  - r10: counter-hint = 27.9ms NULL at 130x less traffic.
//  - r11: adaptive-pace single-shot = 18.1ms BEST (poll-phase waste).
//  - r12: fast-retry NEGATIVE (misses are visibility-limited).
//  - r13: zero-barrier + run-ahead = 35.1ms CATASTROPHIC. Lockstep barriers
//    ARE the cadence stabilizer in a globally-coupled recurrence.
//  - r14: slow decay = 21.4ms REGRESSION. Self-timed feedback: pace has no
//    downward force except decay; slow decay -> jitter bumps persist ->
//    equilibrium period inflates. Decay must be fast; probing must be cheap.

#define S_LEN   8192
#define D_INP   1024
#define HDIM    2048
#define FH      8192
#define NWG     256
#define TPB     256
#define XB      8
#define PACE_MAX 120
#define PROBE_GAP 4

typedef _Float16 half2_t __attribute__((ext_vector_type(2)));

#if defined(__has_builtin)
#if __has_builtin(__builtin_amdgcn_fdot2)
#define HAVE_FDOT2 1
#endif
#endif

__device__ __forceinline__ float fdot2f(uint32_t a, uint32_t b, float c) {
#ifdef HAVE_FDOT2
    return __builtin_amdgcn_fdot2(__builtin_bit_cast(half2_t, a),
                                  __builtin_bit_cast(half2_t, b), c, false);
#else
    half2_t ha = __builtin_bit_cast(half2_t, a);
    half2_t hb = __builtin_bit_cast(half2_t, b);
    c = fmaf((float)ha.x, (float)hb.x, c);
    c = fmaf((float)ha.y, (float)hb.y, c);
    return c;
#endif
}

__device__ __forceinline__ uint32_t pack2(float a, float b) {
    half2_t h;
    h.x = (_Float16)a;
    h.y = (_Float16)b;
    return __builtin_bit_cast(uint32_t, h);
}

__device__ __forceinline__ float sigmoidf_fast(float z) {
    return 1.0f / (1.0f + __expf(-z));
}

__device__ __forceinline__ unsigned long long ald(const unsigned long long* p) {
    return __hip_atomic_load(p, __ATOMIC_RELAXED, __HIP_MEMORY_SCOPE_AGENT);
}

extern "C" __global__ void __launch_bounds__(TPB, 1)
lstm_persist(const float* __restrict__ x, const float* __restrict__ W,
             const float* __restrict__ U, const float* __restrict__ b,
             float* __restrict__ out, unsigned long long* __restrict__ hbuf)
{
    // xl: 8 rows x 32 chunks x 20 words (16 used) = 20 KB
    // hl: 32 chunks x 36 words (32 used)          = 4.5 KB
    // zz: [wave][cg][gate] floats                  = 0.5 KB
    __shared__ __align__(16) uint32_t xl[XB * 640];
    __shared__ __align__(16) uint32_t hl[32 * 36];
    __shared__ __align__(16) float    zz[4 * 8 * 4];

    const int tid = threadIdx.x;
    const int wg  = blockIdx.x;
    const int cg  = tid & 7;     // h-index within WG octet
    const int kc  = tid >> 3;    // k-chunk 0..31
    const int w   = tid >> 6;    // wave 0..3

    // ---- one-time: weights -> registers (FULL unroll, static indices) ----
    uint32_t ureg[4][32];
    uint32_t wreg[4][16];
#pragma unroll
    for (int g = 0; g < 4; ++g) {
        const int col = g * HDIM + wg * 8 + cg;
#pragma unroll
        for (int p = 0; p < 32; ++p) {
            const int k0 = kc * 64 + 2 * p;
            ureg[g][p] = pack2(U[(size_t)k0 * FH + col],
                               U[(size_t)(k0 + 1) * FH + col]);
        }
#pragma unroll
        for (int p = 0; p < 16; ++p) {
            const int k0 = kc * 32 + 2 * p;
            wreg[g][p] = pack2(W[(size_t)k0 * FH + col],
                               W[(size_t)(k0 + 1) * FH + col]);
        }
    }
    float bias[4] = {0.f, 0.f, 0.f, 0.f};
    if (tid < 8) {
#pragma unroll
        for (int g = 0; g < 4; ++g) bias[g] = b[g * HDIM + wg * 8 + cg];
    }
    float cst = 0.0f;   // cell state for h-index cg (valid on tid<8)

    // ---- x prefetch regs: row r = tid>>5, chunk kcw = tid&31 ----
    const int xr  = tid >> 5;
    const int kcw = tid & 31;
    float4 pf[8];
    {
        const float4* src = (const float4*)(x + (size_t)xr * D_INP + kcw * 32);
#pragma unroll
        for (int q = 0; q < 8; ++q) pf[q] = src[q];
    }

    // hbuf: 2 parity buffers x 256 producers x 4 u64 {tag32|f16x2}
    unsigned long long* const hb0 = hbuf;
    unsigned long long* const hb1 = hbuf + 1024;

    int pace = 0;   // adaptive pre-sleep units (wave-uniform updates)

    for (int t = 0; t < S_LEN; ++t) {
        const int s = t & (XB - 1);
        if (s == 0) {
            // commit prefetched x rows [t, t+8) to LDS as f16x2
            uint32_t* dst = &xl[xr * 640 + kcw * 20];
#pragma unroll
            for (int q = 0; q < 4; ++q) {
                uint4 v;
                v.x = pack2(pf[2 * q].x, pf[2 * q].y);
                v.y = pack2(pf[2 * q].z, pf[2 * q].w);
                v.z = pack2(pf[2 * q + 1].x, pf[2 * q + 1].y);
                v.w = pack2(pf[2 * q + 1].z, pf[2 * q + 1].w);
                *(uint4*)(dst + q * 4) = v;
            }
            __syncthreads();
            if (t + XB < S_LEN) {   // issue next block's loads (8 steps ahead)
                const float4* src = (const float4*)(
                    x + (size_t)(t + XB + xr) * D_INP + kcw * 32);
#pragma unroll
                for (int q = 0; q < 8; ++q) pf[q] = src[q];
            }
        }

        // ---- split sleep; issue PROBE batch early, SAFE batch on time ----
        unsigned long long* const gsrc = ((t & 1) ? hb1 : hb0) + tid * 4;
        unsigned long long p0, p1, p2, p3;   // probe
        unsigned long long a0, a1, a2, a3;   // safe
        if (t > 0) {
            const int ps = (pace > PROBE_GAP) ? (pace - PROBE_GAP) : 0;
            for (int i = 0; i < ps; ++i) __builtin_amdgcn_s_sleep(1);
            p0 = ald(gsrc + 0); p1 = ald(gsrc + 1);
            p2 = ald(gsrc + 2); p3 = ald(gsrc + 3);
            const int rem = pace - ps;
            for (int i = 0; i < rem; ++i) __builtin_amdgcn_s_sleep(1);
            a0 = ald(gsrc + 0); a1 = ald(gsrc + 1);
            a2 = ald(gsrc + 2); a3 = ald(gsrc + 3);
        }

        // ---- x-part: acc[g] = sum_k x_t[k] * W[k, col(g)] (loads fly) ----
        float acc[4] = {0.f, 0.f, 0.f, 0.f};
        {
            uint32_t xp[16];
            const uint32_t* xpp = &xl[s * 640 + kc * 20];
            *(uint4*)&xp[0]  = *(const uint4*)(xpp + 0);
            *(uint4*)&xp[4]  = *(const uint4*)(xpp + 4);
            *(uint4*)&xp[8]  = *(const uint4*)(xpp + 8);
            *(uint4*)&xp[12] = *(const uint4*)(xpp + 12);
#pragma unroll
            for (int p = 0; p < 16; ++p) {
#pragma unroll
                for (int g = 0; g < 4; ++g)
                    acc[g] = fdot2f(wreg[g][p], xp[p], acc[g]);
            }
        }

        // ---- resolve gather: probe -> safe -> fallback ----
        if (t > 0) {
            const unsigned int want = (unsigned int)t;
            uint4 q4;
            const bool ph = ((unsigned int)(p0 >> 32) == want) &
                            ((unsigned int)(p1 >> 32) == want) &
                            ((unsigned int)(p2 >> 32) == want) &
                            ((unsigned int)(p3 >> 32) == want);
            if (__all(ph)) {
                if (pace > 0) pace -= 1;       // boundary hug, free probe
                q4.x = (unsigned int)p0; q4.y = (unsigned int)p1;
                q4.z = (unsigned int)p2; q4.w = (unsigned int)p3;
            } else {
                const bool ah = ((unsigned int)(a0 >> 32) == want) &
                                ((unsigned int)(a1 >> 32) == want) &
                                ((unsigned int)(a2 >> 32) == want) &
                                ((unsigned int)(a3 >> 32) == want);
                if (!__all(ah)) {
                    // true straggler event: bump allowance + paced fallback
                    pace = (pace + 8 > PACE_MAX) ? PACE_MAX : pace + 8;
                    int guard = 0;
                    for (;;) {
                        a0 = ald(gsrc + 0); a1 = ald(gsrc + 1);
                        a2 = ald(gsrc + 2); a3 = ald(gsrc + 3);
                        const bool ok = ((unsigned int)(a0 >> 32) == want) &
                                        ((unsigned int)(a1 >> 32) == want) &
                                        ((unsigned int)(a2 >> 32) == want) &
                                        ((unsigned int)(a3 >> 32) == want);
                        if (ok || ++guard >= (1 << 20)) break;   // never hang
                        __builtin_amdgcn_s_sleep(1);
                    }
                }
                q4.x = (unsigned int)a0; q4.y = (unsigned int)a1;
                q4.z = (unsigned int)a2; q4.w = (unsigned int)a3;
            }
            *(uint4*)&hl[kc * 36 + cg * 4] = q4;   // (tid>>3, tid&7)
        } else {
            const uint4 z4 = {0u, 0u, 0u, 0u};
            *(uint4*)&hl[kc * 36 + cg * 4] = z4;
        }
        __syncthreads();   // barrier A: hl ready

        // ---- recurrent part: acc[g] += sum_k h_t[k] * U[k, col(g)] ----
        {
            const uint32_t* hp = &hl[kc * 36];
#pragma unroll
            for (int q = 0; q < 8; ++q) {
                const uint4 hv = *(const uint4*)(hp + q * 4);
#pragma unroll
                for (int g = 0; g < 4; ++g) {
                    acc[g] = fdot2f(ureg[g][4 * q + 0], hv.x, acc[g]);
                    acc[g] = fdot2f(ureg[g][4 * q + 1], hv.y, acc[g]);
                    acc[g] = fdot2f(ureg[g][4 * q + 2], hv.z, acc[g]);
                    acc[g] = fdot2f(ureg[g][4 * q + 3], hv.w, acc[g]);
                }
            }
        }

        // ---- butterfly over in-wave kc (tid bits 3..5) ----
#pragma unroll
        for (int g = 0; g < 4; ++g) {
            acc[g] += __shfl_xor(acc[g], 8);
            acc[g] += __shfl_xor(acc[g], 16);
            acc[g] += __shfl_xor(acc[g], 32);
        }
        if ((tid & 63) < 8) {
            float4 vv = {acc[0], acc[1], acc[2], acc[3]};
            *(float4*)&zz[(w * 8 + cg) * 4] = vv;
        }
        __syncthreads();   // barrier B: zz ready (also fences hl reuse)

        // ---- final reduce + gates + publish (threads 0..7) ----
        if (tid < 8) {
            const float4 z0 = *(const float4*)&zz[(0 + cg) * 4];
            const float4 z1 = *(const float4*)&zz[(8 + cg) * 4];
            const float4 z2 = *(const float4*)&zz[(16 + cg) * 4];
            const float4 z3 = *(const float4*)&zz[(24 + cg) * 4];
            const float zi = bias[0] + z0.x + z1.x + z2.x + z3.x;
            const float zf = bias[1] + z0.y + z1.y + z2.y + z3.y;
            const float zg = bias[2] + z0.z + z1.z + z2.z + z3.z;
            const float zo = bias[3] + z0.w + z1.w + z2.w + z3.w;
            const float si = sigmoidf_fast(zi);
            const float sf = sigmoidf_fast(zf);
            const float so = sigmoidf_fast(zo);
            const float cn = sf * cst + si * zg;   // linear candidate act
            cst = cn;
            const float hn = so * cn;              // linear output act
            if (t < S_LEN - 1) {
                // pack pairs: lane j<4 publishes {tag, h[2j], h[2j+1]}
                const float ha  = __shfl(hn, 2 * cg);
                const float hbv = __shfl(hn, 2 * cg + 1);
                if (cg < 4) {
                    const unsigned long long pv =
                        ((unsigned long long)(unsigned int)(t + 1) << 32) |
                        (unsigned long long)pack2(ha, hbv);
                    unsigned long long* const dst =
                        (((t + 1) & 1) ? hb1 : hb0) + wg * 4 + cg;
                    __hip_atomic_store(dst, pv, __ATOMIC_RELAXED,
                                       __HIP_MEMORY_SCOPE_AGENT);
                }
            } else {
                out[wg * 8 + cg] = hn;
            }
        }
    }
}

extern "C" void kernel_launch(void* const* d_in, const int* in_sizes, int n_in,
                              void* d_out, int out_size, void* d_ws, size_t ws_size,
                              hipStream_t stream) {
    const float* x = (const float*)d_in[0];
    const float* W = (const float*)d_in[1];
    const float* U = (const float*)d_in[2];
    const float* b = (const float*)d_in[3];
    unsigned long long* hbuf = (unsigned long long*)d_ws;

    // Reset exchange tags every launch (replays must re-synchronize for real).
    (void)hipMemsetAsync(hbuf, 0, (size_t)2 * 1024 * sizeof(unsigned long long),
                         stream);

    hipLaunchKernelGGL(lstm_persist, dim3(NWG), dim3(TPB), 0, stream,
                       x, W, U, b, (float*)d_out, hbuf);
}

// Round 16
// 17752.074 us; speedup vs baseline: 1.2297x; 1.2297x over previous
//
#include <hip/hip_runtime.h>
#include <stdint.h>

// LSTM (linear cell/output act) h_last. S=8192, D_IN=1024, H=2048.
// Persistent: 256 WGs x 256 thr, 1 WG/CU. WG owns 8 h-indices (32 cols).
// Thread (kc=tid>>3, cg=tid&7): 4 gate-cols of h-index cg, k-chunk kc.
//   U slice in regs ureg[4][32], W slice in regs wreg[4][16] (f16x2).
// Exchange: producer WG publishes 8 h as FOUR u64 {tag32|f16x2} (32 B).
// GATHER: adaptive-pace single-shot (r11, VERIFIED 18.1ms BEST) — sleep
// pace x s_sleep(1), issue ONE 32B batch, overlap with x-dot, check once;
// controller miss:+8 / hit:-1. Fallback on miss = paced poll.
// THIS IS THE EXACT r11 KERNEL RESTORED. Four consecutive attempts to
// improve its gather dynamics all regressed — the controller's equilibrium
// is a sharp local optimum:
// POST-MORTEM LEDGER:
//  - r2: partial unroll -> ureg/wreg in scratch (VGPR=80, 207GB, 2.7x).
//  - r3: guarded per-slot polls serialize (8 x LLC RT/round).
//  - r4: 64B tight polls -> contention collapse (38ms).
//  - r5: 32B + sleep(2) = 26.2ms best blind-poll design.
//  - r6: depth-2 no-sleep -> 32.3ms (traffic storm).
//  - r7: 8B tag + 32B confirm = 27.7ms (extra serial RT).
//  - r8/r9: sc0 XCD-L2 mirror never engaged; abandoned.
//  - r10: counter-hint = 27.9ms NULL at 130x less traffic.
//  - r11: adaptive-pace single-shot = 18.1ms BEST (killed poll-phase waste).
//  - r12: fast-retry NEGATIVE (+0.4ms): misses are visibility-limited.
//  - r13: zero-barrier run-ahead CATASTROPHIC (+17ms): lockstep barriers ARE
//    the cadence stabilizer in a globally-coupled recurrence.
//  - r14: slow decay (+3.3ms): pace has no downward force except decay;
//    slowing it inflates the self-timed equilibrium.
//  - r15: dual-batch probe (+3.7ms): probe shifts the effective sample point
//    off the converged boundary and doubles the load burst.
// Residual 5.3Kcy/step ≈ delta(400-700) + gather RT(1-1.5K) + dots(~400)
// + reduce/barriers/tail(~600) + straggler-max/sawtooth(~1K) — within
// ~20-40% of the latency-physics floor for an all-to-all coupled step.

#define S_LEN   8192
#define D_INP   1024
#define HDIM    2048
#define FH      8192
#define NWG     256
#define TPB     256
#define XB      8
#define PACE_MAX 120

typedef _Float16 half2_t __attribute__((ext_vector_type(2)));

#if defined(__has_builtin)
#if __has_builtin(__builtin_amdgcn_fdot2)
#define HAVE_FDOT2 1
#endif
#endif

__device__ __forceinline__ float fdot2f(uint32_t a, uint32_t b, float c) {
#ifdef HAVE_FDOT2
    return __builtin_amdgcn_fdot2(__builtin_bit_cast(half2_t, a),
                                  __builtin_bit_cast(half2_t, b), c, false);
#else
    half2_t ha = __builtin_bit_cast(half2_t, a);
    half2_t hb = __builtin_bit_cast(half2_t, b);
    c = fmaf((float)ha.x, (float)hb.x, c);
    c = fmaf((float)ha.y, (float)hb.y, c);
    return c;
#endif
}

__device__ __forceinline__ uint32_t pack2(float a, float b) {
    half2_t h;
    h.x = (_Float16)a;
    h.y = (_Float16)b;
    return __builtin_bit_cast(uint32_t, h);
}

__device__ __forceinline__ float sigmoidf_fast(float z) {
    return 1.0f / (1.0f + __expf(-z));
}

__device__ __forceinline__ unsigned long long ald(const unsigned long long* p) {
    return __hip_atomic_load(p, __ATOMIC_RELAXED, __HIP_MEMORY_SCOPE_AGENT);
}

extern "C" __global__ void __launch_bounds__(TPB, 1)
lstm_persist(const float* __restrict__ x, const float* __restrict__ W,
             const float* __restrict__ U, const float* __restrict__ b,
             float* __restrict__ out, unsigned long long* __restrict__ hbuf)
{
    // xl: 8 rows x 32 chunks x 20 words (16 used) = 20 KB
    // hl: 32 chunks x 36 words (32 used)          = 4.5 KB
    // zz: [wave][cg][gate] floats                  = 0.5 KB
    __shared__ __align__(16) uint32_t xl[XB * 640];
    __shared__ __align__(16) uint32_t hl[32 * 36];
    __shared__ __align__(16) float    zz[4 * 8 * 4];

    const int tid = threadIdx.x;
    const int wg  = blockIdx.x;
    const int cg  = tid & 7;     // h-index within WG octet
    const int kc  = tid >> 3;    // k-chunk 0..31
    const int w   = tid >> 6;    // wave 0..3

    // ---- one-time: weights -> registers (FULL unroll, static indices) ----
    uint32_t ureg[4][32];
    uint32_t wreg[4][16];
#pragma unroll
    for (int g = 0; g < 4; ++g) {
        const int col = g * HDIM + wg * 8 + cg;
#pragma unroll
        for (int p = 0; p < 32; ++p) {
            const int k0 = kc * 64 + 2 * p;
            ureg[g][p] = pack2(U[(size_t)k0 * FH + col],
                               U[(size_t)(k0 + 1) * FH + col]);
        }
#pragma unroll
        for (int p = 0; p < 16; ++p) {
            const int k0 = kc * 32 + 2 * p;
            wreg[g][p] = pack2(W[(size_t)k0 * FH + col],
                               W[(size_t)(k0 + 1) * FH + col]);
        }
    }
    float bias[4] = {0.f, 0.f, 0.f, 0.f};
    if (tid < 8) {
#pragma unroll
        for (int g = 0; g < 4; ++g) bias[g] = b[g * HDIM + wg * 8 + cg];
    }
    float cst = 0.0f;   // cell state for h-index cg (valid on tid<8)

    // ---- x prefetch regs: row r = tid>>5, chunk kcw = tid&31 ----
    const int xr  = tid >> 5;
    const int kcw = tid & 31;
    float4 pf[8];
    {
        const float4* src = (const float4*)(x + (size_t)xr * D_INP + kcw * 32);
#pragma unroll
        for (int q = 0; q < 8; ++q) pf[q] = src[q];
    }

    // hbuf: 2 parity buffers x 256 producers x 4 u64 {tag32|f16x2}
    unsigned long long* const hb0 = hbuf;
    unsigned long long* const hb1 = hbuf + 1024;

    int pace = 0;   // adaptive pre-sleep units (wave-uniform updates)

    for (int t = 0; t < S_LEN; ++t) {
        const int s = t & (XB - 1);
        if (s == 0) {
            // commit prefetched x rows [t, t+8) to LDS as f16x2
            uint32_t* dst = &xl[xr * 640 + kcw * 20];
#pragma unroll
            for (int q = 0; q < 4; ++q) {
                uint4 v;
                v.x = pack2(pf[2 * q].x, pf[2 * q].y);
                v.y = pack2(pf[2 * q].z, pf[2 * q].w);
                v.z = pack2(pf[2 * q + 1].x, pf[2 * q + 1].y);
                v.w = pack2(pf[2 * q + 1].z, pf[2 * q + 1].w);
                *(uint4*)(dst + q * 4) = v;
            }
            __syncthreads();
            if (t + XB < S_LEN) {   // issue next block's loads (8 steps ahead)
                const float4* src = (const float4*)(
                    x + (size_t)(t + XB + xr) * D_INP + kcw * 32);
#pragma unroll
                for (int q = 0; q < 8; ++q) pf[q] = src[q];
            }
        }

        // ---- calibrated pre-sleep, then issue the single gather batch ----
        unsigned long long* const gsrc = ((t & 1) ? hb1 : hb0) + tid * 4;
        unsigned long long a0, a1, a2, a3;
        if (t > 0) {
            for (int i = 0; i < pace; ++i) __builtin_amdgcn_s_sleep(1);
            a0 = ald(gsrc + 0); a1 = ald(gsrc + 1);
            a2 = ald(gsrc + 2); a3 = ald(gsrc + 3);
        }

        // ---- x-part: acc[g] = sum_k x_t[k] * W[k, col(g)] (loads fly) ----
        float acc[4] = {0.f, 0.f, 0.f, 0.f};
        {
            uint32_t xp[16];
            const uint32_t* xpp = &xl[s * 640 + kc * 20];
            *(uint4*)&xp[0]  = *(const uint4*)(xpp + 0);
            *(uint4*)&xp[4]  = *(const uint4*)(xpp + 4);
            *(uint4*)&xp[8]  = *(const uint4*)(xpp + 8);
            *(uint4*)&xp[12] = *(const uint4*)(xpp + 12);
#pragma unroll
            for (int p = 0; p < 16; ++p) {
#pragma unroll
                for (int g = 0; g < 4; ++g)
                    acc[g] = fdot2f(wreg[g][p], xp[p], acc[g]);
            }
        }

        // ---- gather h_t: single-shot check + controller + fallback poll ----
        if (t > 0) {
            const unsigned int want = (unsigned int)t;
            const bool hit = ((unsigned int)(a0 >> 32) == want) &
                             ((unsigned int)(a1 >> 32) == want) &
                             ((unsigned int)(a2 >> 32) == want) &
                             ((unsigned int)(a3 >> 32) == want);
            if (__all(hit)) {
                if (pace > 0) pace -= 1;      // shrink slowly toward boundary
            } else {
                pace = (pace + 8 > PACE_MAX) ? PACE_MAX : pace + 8;
                int guard = 0;
                for (;;) {                     // r5 fallback poll
                    a0 = ald(gsrc + 0); a1 = ald(gsrc + 1);
                    a2 = ald(gsrc + 2); a3 = ald(gsrc + 3);
                    const bool ok = ((unsigned int)(a0 >> 32) == want) &
                                    ((unsigned int)(a1 >> 32) == want) &
                                    ((unsigned int)(a2 >> 32) == want) &
                                    ((unsigned int)(a3 >> 32) == want);
                    if (ok || ++guard >= (1 << 20)) break;   // never hang
                    __builtin_amdgcn_s_sleep(1);
                }
            }
            uint4 q4;
            q4.x = (unsigned int)a0;   // low u32 IS the f16x2 hl word
            q4.y = (unsigned int)a1;
            q4.z = (unsigned int)a2;
            q4.w = (unsigned int)a3;
            *(uint4*)&hl[kc * 36 + cg * 4] = q4;   // (tid>>3, tid&7)
        } else {
            const uint4 z4 = {0u, 0u, 0u, 0u};
            *(uint4*)&hl[kc * 36 + cg * 4] = z4;
        }
        __syncthreads();   // barrier A: hl ready

        // ---- recurrent part: acc[g] += sum_k h_t[k] * U[k, col(g)] ----
        {
            const uint32_t* hp = &hl[kc * 36];
#pragma unroll
            for (int q = 0; q < 8; ++q) {
                const uint4 hv = *(const uint4*)(hp + q * 4);
#pragma unroll
                for (int g = 0; g < 4; ++g) {
                    acc[g] = fdot2f(ureg[g][4 * q + 0], hv.x, acc[g]);
                    acc[g] = fdot2f(ureg[g][4 * q + 1], hv.y, acc[g]);
                    acc[g] = fdot2f(ureg[g][4 * q + 2], hv.z, acc[g]);
                    acc[g] = fdot2f(ureg[g][4 * q + 3], hv.w, acc[g]);
                }
            }
        }

        // ---- butterfly over in-wave kc (tid bits 3..5) ----
#pragma unroll
        for (int g = 0; g < 4; ++g) {
            acc[g] += __shfl_xor(acc[g], 8);
            acc[g] += __shfl_xor(acc[g], 16);
            acc[g] += __shfl_xor(acc[g], 32);
        }
        if ((tid & 63) < 8) {
            float4 vv = {acc[0], acc[1], acc[2], acc[3]};
            *(float4*)&zz[(w * 8 + cg) * 4] = vv;
        }
        __syncthreads();   // barrier B: zz ready (also fences hl reuse)

        // ---- final reduce + gates + publish (threads 0..7) ----
        if (tid < 8) {
            const float4 z0 = *(const float4*)&zz[(0 + cg) * 4];
            const float4 z1 = *(const float4*)&zz[(8 + cg) * 4];
            const float4 z2 = *(const float4*)&zz[(16 + cg) * 4];
            const float4 z3 = *(const float4*)&zz[(24 + cg) * 4];
            const float zi = bias[0] + z0.x + z1.x + z2.x + z3.x;
            const float zf = bias[1] + z0.y + z1.y + z2.y + z3.y;
            const float zg = bias[2] + z0.z + z1.z + z2.z + z3.z;
            const float zo = bias[3] + z0.w + z1.w + z2.w + z3.w;
            const float si = sigmoidf_fast(zi);
            const float sf = sigmoidf_fast(zf);
            const float so = sigmoidf_fast(zo);
            const float cn = sf * cst + si * zg;   // linear candidate act
            cst = cn;
            const float hn = so * cn;              // linear output act
            if (t < S_LEN - 1) {
                // pack pairs: lane j<4 publishes {tag, h[2j], h[2j+1]}
                const float ha  = __shfl(hn, 2 * cg);
                const float hbv = __shfl(hn, 2 * cg + 1);
                if (cg < 4) {
                    const unsigned long long pv =
                        ((unsigned long long)(unsigned int)(t + 1) << 32) |
                        (unsigned long long)pack2(ha, hbv);
                    unsigned long long* const dst =
                        (((t + 1) & 1) ? hb1 : hb0) + wg * 4 + cg;
                    __hip_atomic_store(dst, pv, __ATOMIC_RELAXED,
                                       __HIP_MEMORY_SCOPE_AGENT);
                }
            } else {
                out[wg * 8 + cg] = hn;
            }
        }
    }
}

extern "C" void kernel_launch(void* const* d_in, const int* in_sizes, int n_in,
                              void* d_out, int out_size, void* d_ws, size_t ws_size,
                              hipStream_t stream) {
    const float* x = (const float*)d_in[0];
    const float* W = (const float*)d_in[1];
    const float* U = (const float*)d_in[2];
    const float* b = (const float*)d_in[3];
    unsigned long long* hbuf = (unsigned long long*)d_ws;

    // Reset exchange tags every launch (replays must re-synchronize for real).
    (void)hipMemsetAsync(hbuf, 0, (size_t)2 * 1024 * sizeof(unsigned long long),
                         stream);

    hipLaunchKernelGGL(lstm_persist, dim3(NWG), dim3(TPB), 0, stream,
                       x, W, U, b, (float*)d_out, hbuf);
}